// Round 8
// baseline (30.468 us; speedup 1.0000x reference)
//
#include <hip/hip_runtime.h>
#include <math.h>

#define BATCH 8192
#define NTASK 1024
#define NF 256
#define NH 64
#define MAXBLK 1920   // max sum ceil(cnt_t/8) <= 1024 + 8192/8 - ... (safe bound)

// d_ws layout (ints): [0,8192) order | [8192, 8192+MAXBLK) desc | [8192+MAXBLK] nblk

// ---------- prep: hist + packed double-scan + scatter + desc, ONE block ----------
__global__ __launch_bounds__(1024) void prep_kernel(const int* __restrict__ task_ids,
                                                    int* __restrict__ order,
                                                    int* __restrict__ desc,
                                                    int* __restrict__ nblk) {
    __shared__ int cnt[NTASK];   // histogram, then scatter cursor
    __shared__ int wsum[16];
    const int tid  = threadIdx.x;
    const int lane = tid & 63;
    const int wv   = tid >> 6;

    cnt[tid] = 0;
    __syncthreads();

    int myids[8];
    #pragma unroll
    for (int k = 0; k < 8; ++k) myids[k] = task_ids[tid + k * 1024];
    #pragma unroll
    for (int k = 0; k < 8; ++k) atomicAdd(&cnt[myids[k]], 1);
    __syncthreads();

    const int c  = cnt[tid];
    const int nb = (c + 7) >> 3;          // blocks of 8 samples
    const int packed = (c << 12) | nb;    // both prefix sums at once

    // inclusive wave-scan (shfl, no barriers)
    int v = packed;
    #pragma unroll
    for (int d = 1; d < 64; d <<= 1) {
        int u = __shfl_up(v, d);
        if (lane >= d) v += u;
    }
    if (lane == 63) wsum[wv] = v;
    __syncthreads();
    if (wv == 0 && lane < 16) {
        int s = wsum[lane];
        #pragma unroll
        for (int d = 1; d < 16; d <<= 1) {
            int u = __shfl_up(s, d);
            if (lane >= d) s += u;
        }
        wsum[lane] = s;                   // inclusive wave sums
    }
    __syncthreads();

    const int incl = ((wv > 0) ? wsum[wv - 1] : 0) + v;
    const int excl = incl - packed;
    const int offC   = excl >> 12;
    const int bstart = excl & 0xFFF;
    if (tid == NTASK - 1) nblk[0] = incl & 0xFFF;
    cnt[tid] = offC;                      // reuse as cursor
    __syncthreads();

    #pragma unroll
    for (int k = 0; k < 8; ++k) {
        int i = tid + k * 1024;
        int pos = atomicAdd(&cnt[myids[k]], 1);
        order[pos] = i;
    }
    for (int k = 0; k < nb; ++k) {
        int S = min(8, c - 8 * k);
        desc[bstart + k] = (tid << 16) | ((offC + 8 * k) << 3) | (S - 1);
    }
}

// ---------- math helpers ----------
__device__ __forceinline__ float gelu_exact(float s) {
    return 0.5f * s * (1.f + erff(s * 0.70710678118654752440f));
}
__device__ __forceinline__ float4 gelu4(float4 v) {
    return make_float4(gelu_exact(v.x), gelu_exact(v.y), gelu_exact(v.z), gelu_exact(v.w));
}
__device__ __forceinline__ float4 fma4(float s, float4 w, float4 a) {
    a.x = fmaf(s, w.x, a.x); a.y = fmaf(s, w.y, a.y);
    a.z = fmaf(s, w.z, a.z); a.w = fmaf(s, w.w, a.w);
    return a;
}
__device__ __forceinline__ float4 xor_reduce4(float4 v, int m) {
    v.x += __shfl_xor(v.x, m); v.y += __shfl_xor(v.y, m);
    v.z += __shfl_xor(v.z, m); v.w += __shfl_xor(v.w, m);
    return v;
}
__device__ __forceinline__ float4 add4(float4 a, float4 b) {
    return make_float4(a.x + b.x, a.y + b.y, a.z + b.z, a.w + b.w);
}

// ---------- main: one block per task-uniform OCTET of samples ----------
// 4 waves. Layer 1: wave w owns f-slice [64w, 64w+64) for ALL 8 samples.
// Layer 2/3: wave w computes samples 2w, 2w+1 (shared W2 loads).
// Lane = (grp = lane>>4 row-slice, cq = lane&15 col-quad). 2 barriers.
__global__ __launch_bounds__(256) void mlp_oct(
    const float* __restrict__ x,
    const int*   __restrict__ order,
    const int*   __restrict__ desc,
    const int*   __restrict__ nblk,
    const float* __restrict__ l1_emb,
    const float* __restrict__ l2_emb,
    const float* __restrict__ l3_emb,
    float*       __restrict__ out)
{
    const int nb = nblk[0];
    const int P  = blockIdx.x;
    if (P >= nb) return;
    // bijective XCD-chunked swizzle for runtime nb (m204 variant)
    const int qc = nb >> 3, r = nb & 7;
    const int xcd = P & 7, j = P >> 3;
    const int b = (xcd < r ? xcd * (qc + 1) : r * (qc + 1) + (xcd - r) * qc) + j;

    const int d  = desc[b];
    const int S  = (d & 7) + 1;
    const int st = (d >> 3) & 8191;
    const int t  = d >> 16;

    const int tid  = threadIdx.x;
    const int lane = tid & 63;
    const int w    = tid >> 6;
    const int cq   = lane & 15;
    const int grp  = lane >> 4;

    __shared__ float  xs[8][NF];        // 8 KB
    __shared__ float4 red[4][8][16];    // 8 KB  [wave][sample][quad]

    // wave-uniform sample indices: wave w stages rows w and w+4,
    // computes layers 2/3 for samples 2w, 2w+1.
    const int iA = order[st + min(w,     S - 1)];
    const int iB = order[st + min(w + 4, S - 1)];
    const int i0 = order[st + min(2 * w,     S - 1)];
    const int i1 = order[st + min(2 * w + 1, S - 1)];

    // stage x rows w and w+4
    {
        const float4* x4 = (const float4*)x;
        ((float4*)xs)[w * 64 + lane]         = x4[(size_t)iA * 64 + lane];
        ((float4*)xs)[(w + 4) * 64 + lane]   = x4[(size_t)iB * 64 + lane];
    }

    // prefetch layer-2/3 weights into registers (depend only on t):
    // latency hides under layer-1 compute.
    const float4* W2 = (const float4*)(l2_emb + (size_t)t * (NH * NH)); // [64][16]
    const float4* L3 = (const float4*)(l3_emb + (size_t)t * NH);
    const float4 w2q0 = W2[(grp * 4 + 0) * 16 + cq];
    const float4 w2q1 = W2[(grp * 4 + 1) * 16 + cq];
    const float4 w2q2 = W2[(grp * 4 + 2) * 16 + cq];
    const float4 w2q3 = W2[(grp * 4 + 3) * 16 + cq];
    const float4 w3   = L3[cq];

    __syncthreads();

    // ---- layer 1: wave w covers f-slice [64w, 64w+64), 8 samples ----
    const float4* W1 = (const float4*)(l1_emb + (size_t)t * (NF * NH)); // [256][16]
    float4 acc[8];
    #pragma unroll
    for (int s = 0; s < 8; ++s) acc[s] = make_float4(0.f, 0.f, 0.f, 0.f);
    const int fbase = w * 64 + grp * 16;
    #pragma unroll
    for (int jj = 0; jj < 16; ++jj) {
        const int f = fbase + jj;
        float4 wv = W1[f * 16 + cq];
        #pragma unroll
        for (int s = 0; s < 8; ++s)
            acc[s] = fma4(xs[s][f], wv, acc[s]);
    }
    #pragma unroll
    for (int s = 0; s < 8; ++s)
        acc[s] = xor_reduce4(xor_reduce4(acc[s], 16), 32);
    if (lane < 16) {
        #pragma unroll
        for (int s = 0; s < 8; ++s) red[w][s][lane] = acc[s];
    }
    __syncthreads();

    // finalize h1 quad `grp` for this wave's two samples (redundant across cq)
    const float4 hv0 = gelu4(add4(add4(red[0][2*w][grp],   red[1][2*w][grp]),
                                  add4(red[2][2*w][grp],   red[3][2*w][grp])));
    const float4 hv1 = gelu4(add4(add4(red[0][2*w+1][grp], red[1][2*w+1][grp]),
                                  add4(red[2][2*w+1][grp], red[3][2*w+1][grp])));

    // ---- layer 2: shared W2 registers feed both samples ----
    float4 b0 = make_float4(0.f, 0.f, 0.f, 0.f);
    float4 b1 = make_float4(0.f, 0.f, 0.f, 0.f);
    b0 = fma4(hv0.x, w2q0, b0);  b1 = fma4(hv1.x, w2q0, b1);
    b0 = fma4(hv0.y, w2q1, b0);  b1 = fma4(hv1.y, w2q1, b1);
    b0 = fma4(hv0.z, w2q2, b0);  b1 = fma4(hv1.z, w2q2, b1);
    b0 = fma4(hv0.w, w2q3, b0);  b1 = fma4(hv1.w, w2q3, b1);
    b0 = xor_reduce4(xor_reduce4(b0, 16), 32);
    b1 = xor_reduce4(xor_reduce4(b1, 16), 32);
    float4 g0 = gelu4(b0);
    float4 g1 = gelu4(b1);

    // ---- layer 3 ----
    float d0 = g0.x * w3.x + g0.y * w3.y + g0.z * w3.z + g0.w * w3.w;
    float d1 = g1.x * w3.x + g1.y * w3.y + g1.z * w3.z + g1.w * w3.w;
    #pragma unroll
    for (int m = 1; m < 16; m <<= 1) {
        d0 += __shfl_xor(d0, m);
        d1 += __shfl_xor(d1, m);
    }
    if (lane == 0) {
        if (2 * w < S)     out[i0] = 1.f / (1.f + expf(-d0));
        if (2 * w + 1 < S) out[i1] = 1.f / (1.f + expf(-d1));
    }
}

extern "C" void kernel_launch(void* const* d_in, const int* in_sizes, int n_in,
                              void* d_out, int out_size, void* d_ws, size_t ws_size,
                              hipStream_t stream) {
    const float* x        = (const float*)d_in[0];
    const int*   task_ids = (const int*)  d_in[1];
    const float* l1_emb   = (const float*)d_in[2];
    const float* l2_emb   = (const float*)d_in[3];
    const float* l3_emb   = (const float*)d_in[4];
    float*       out      = (float*)d_out;

    int* ws    = (int*)d_ws;
    int* order = ws;                 // [0, 8192)
    int* desc  = ws + BATCH;         // [8192, 8192+MAXBLK)
    int* nblk  = ws + BATCH + MAXBLK;

    prep_kernel<<<1, 1024, 0, stream>>>(task_ids, order, desc, nblk);
    mlp_oct    <<<MAXBLK, 256, 0, stream>>>(x, order, desc, nblk,
                                            l1_emb, l2_emb, l3_emb, out);
}